// Round 2
// 345.552 us; speedup vs baseline: 1.0325x; 1.0325x over previous
//
#include <hip/hip_runtime.h>
#include <stdint.h>

#define N_NODES  100000
#define N_EDGES  1600000
#define IN_FEATS 128
#define HID      32
#define N_REL    5
#define N_BASES  2
#define N_PAIRS  4096

#define NB        196        // buckets of 512 dst nodes
#define BCAP      16384      // fixed slab per bucket (mean 8192, sigma ~90)
#define EPB       2048       // edges per scatter block
#define SC_BLOCKS 782        // ceil(1600000/2048)
#define TL1_BLOCKS 1250      // 6250 groups / 5
#define NGROUPS   6250       // N_NODES/16

typedef __attribute__((ext_vector_type(8))) short short8;
typedef __attribute__((ext_vector_type(4))) float f32x4;

__device__ inline unsigned int pack_bf16(float a, float b) {
    unsigned int ua = __float_as_uint(a), ub = __float_as_uint(b);
    ua = (ua + 0x7fffu + ((ua >> 16) & 1u)) >> 16;
    ub = (ub + 0x7fffu + ((ub >> 16) & 1u)) >> 16;
    return ua | (ub << 16);
}

__device__ inline unsigned short bf16_1(float a) {
    unsigned int u = __float_as_uint(a);
    u = (u + 0x7fffu + ((u >> 16) & 1u)) >> 16;
    return (unsigned short)u;
}

// ---------------- weight prep (144 blocks) + gcur zeroing ----------------

__global__ __launch_bounds__(256) void k_wprep(
    const float* __restrict__ V1, const float* __restrict__ comp1, const float* __restrict__ loop1,
    const float* __restrict__ V2, const float* __restrict__ comp2, const float* __restrict__ loop2,
    const float* __restrict__ V3, const float* __restrict__ comp3, const float* __restrict__ loop3,
    unsigned short* __restrict__ Wbf1, unsigned short* __restrict__ Wbf2,
    unsigned short* __restrict__ Wbf3, int* __restrict__ gcur) {
    int b = blockIdx.x;
    int t = threadIdx.x;
    if (b == 0 && t < NB) gcur[t] = 0;
    const float *V, *comp, *loopw;
    unsigned short* Wbf;
    int D, idx;
    if (b < 96)      { V = V1; comp = comp1; loopw = loop1; Wbf = Wbf1; D = IN_FEATS; idx = b * 256 + t; }
    else if (b < 120){ V = V2; comp = comp2; loopw = loop2; Wbf = Wbf2; D = HID;      idx = (b - 96) * 256 + t; }
    else             { V = V3; comp = comp3; loopw = loop3; Wbf = Wbf3; D = HID;      idx = (b - 120) * 256 + t; }
    if (idx >= 192 * D) return;
    int j = idx / D, k = idx % D;
    float v;
    if (j < 160) {
        int r = j >> 5, o = j & 31;
        v = comp[r * 2 + 0] * V[(size_t)(0 * D + k) * 32 + o]
          + comp[r * 2 + 1] * V[(size_t)(1 * D + k) * 32 + o];
    } else {
        v = loopw[k * 32 + (j - 160)];
    }
    Wbf[idx] = bf16_1(v);
}

// ---------------- FUSED: edge scatter (blocks 0..781) + transform L1 (blocks 782..2031) ----------
// scatter record: x = (dst&511)<<23 | (src*80 + etype*16), y = mask fp32

__global__ __launch_bounds__(256) void k_fused1(
    const int* __restrict__ src, const int* __restrict__ dst,
    const int* __restrict__ etype, const float* __restrict__ mask,
    int* __restrict__ gcur, int2* __restrict__ ebuf,
    const float* __restrict__ xin,
    const unsigned short* __restrict__ Wbf, const float* __restrict__ bias,
    unsigned short* __restrict__ xs16, float* __restrict__ aggout) {
    int b = blockIdx.x;
    int t = threadIdx.x;
    if (b < SC_BLOCKS) {
        // ---------- scatter with block-local counting sort ----------
        __shared__ int lh[NB];
        __shared__ int lex[NB];
        __shared__ int gbase[NB];
        __shared__ int scanbuf[256];
        __shared__ int2  srec[EPB];
        __shared__ short sb[EPB];
        int e0 = b * EPB;
        if (t < NB) lh[t] = 0;
        __syncthreads();
        int2 rec[8];
        int  bk[8];
#pragma unroll
        for (int i = 0; i < 8; i++) {
            int e = e0 + t + i * 256;
            if (e < N_EDGES) {
                int d = dst[e];
                bk[i] = d >> 9;
                rec[i].x = ((d & 511) << 23) | (src[e] * 80 + etype[e] * 16);
                rec[i].y = __float_as_int(mask[e]);
                atomicAdd(&lh[bk[i]], 1);
            } else bk[i] = -1;
        }
        __syncthreads();
        int cnt = (t < NB) ? lh[t] : 0;
        scanbuf[t] = cnt;
        __syncthreads();
        for (int off = 1; off < 256; off <<= 1) {
            int v = (t >= off) ? scanbuf[t - off] : 0;
            __syncthreads();
            scanbuf[t] += v;
            __syncthreads();
        }
        if (t < NB) {
            lex[t] = scanbuf[t] - cnt;
            gbase[t] = t * BCAP + (cnt ? atomicAdd(&gcur[t], cnt) : 0);
            lh[t] = 0;
        }
        __syncthreads();
#pragma unroll
        for (int i = 0; i < 8; i++) {
            if (bk[i] >= 0) {
                int p = lex[bk[i]] + atomicAdd(&lh[bk[i]], 1);
                srec[p] = rec[i];
                sb[p] = (short)bk[i];
            }
        }
        __syncthreads();
        int total = scanbuf[NB - 1];
        for (int idx = t; idx < total; idx += 256) {
            int bb = sb[idx];
            ebuf[gbase[bb] + (idx - lex[bb])] = srec[idx];
        }
        return;
    }
    // ---------- transform L1 (D=128): wave-specialized MFMA ----------
    __shared__ unsigned short As[16 * 136];
    int bb = b - SC_BLOCKS;
    int wv = t >> 6, lane = t & 63;
    int q = lane >> 4, n16 = lane & 15;
    short8 bfr[3][4];
#pragma unroll
    for (int i = 0; i < 3; i++) {
        int tt = wv * 3 + i;
#pragma unroll
        for (int ks = 0; ks < 4; ks++)
            bfr[i][ks] = *(const short8*)(Wbf + (tt * 16 + n16) * 128 + ks * 32 + q * 8);
    }
    float bv0 = bias[n16], bv1 = bias[16 + n16];
    int node_l = t >> 4;
    int seg    = t & 15;
    int g0 = bb * 5;
    float4 p0, p1;
    {
        const float* xr = xin + ((size_t)(g0 * 16 + node_l)) * 128 + seg * 8;
        p0 = *(const float4*)xr;
        p1 = *(const float4*)(xr + 4);
    }
    for (int gi = 0; gi < 5; gi++) {
        int g = g0 + gi;
        int n0 = g * 16;
        __syncthreads();
        {
            unsigned int u0 = pack_bf16(p0.x, p0.y);
            unsigned int u1 = pack_bf16(p0.z, p0.w);
            unsigned int u2 = pack_bf16(p1.x, p1.y);
            unsigned int u3 = pack_bf16(p1.z, p1.w);
            uint4 v; v.x = u0; v.y = u1; v.z = u2; v.w = u3;
            *(uint4*)(As + node_l * 136 + seg * 8) = v;
        }
        __syncthreads();
        if (gi + 1 < 5) {
            const float* xr = xin + ((size_t)((g + 1) * 16 + node_l)) * 128 + seg * 8;
            p0 = *(const float4*)xr;
            p1 = *(const float4*)(xr + 4);
        }
        short8 afr[4];
#pragma unroll
        for (int ks = 0; ks < 4; ks++)
            afr[ks] = *(const short8*)(As + n16 * 136 + ks * 32 + q * 8);
        f32x4 d[3];
        f32x4 z = {0.f, 0.f, 0.f, 0.f};
#pragma unroll
        for (int i = 0; i < 3; i++) d[i] = z;
#pragma unroll
        for (int i = 0; i < 3; i++)
#pragma unroll
            for (int ks = 0; ks < 4; ks++)
                d[i] = __builtin_amdgcn_mfma_f32_16x16x32_bf16(afr[ks], bfr[i][ks], d[i], 0, 0, 0);
#pragma unroll
        for (int i = 0; i < 3; i++) {
            int tt = wv * 3 + i;
            if (tt < 10) {
#pragma unroll
                for (int r = 0; r < 4; r++) {
                    int node = n0 + q * 4 + r;
                    xs16[(size_t)node * 160 + tt * 16 + n16] = bf16_1(d[i][r]);
                }
            } else {
                float bv = (tt == 10) ? bv0 : bv1;
                int o = (tt - 10) * 16 + n16;
#pragma unroll
                for (int r = 0; r < 4; r++) {
                    int node = n0 + q * 4 + r;
                    aggout[(size_t)node * 32 + o] = d[i][r] + bv;
                }
            }
        }
    }
}

// ---------------- per-half-bucket counting sort -> contiguous CSR (esort + offsets) ----------------

__global__ __launch_bounds__(512) void k_bsort2(
    const int* __restrict__ gcur, const int2* __restrict__ ebuf,
    int2* __restrict__ esort, int* __restrict__ offsets) {
    __shared__ int hist[512];
    __shared__ int incl[512];
    __shared__ int cur[512];
    __shared__ int bs[256];
    __shared__ int sBase, sCnt;
    int blk = blockIdx.x, b = blk >> 1, h = blk & 1, t = threadIdx.x;
    if (t < 256) bs[t] = (t < NB) ? gcur[t] : 0;
    __syncthreads();
    for (int off = 1; off < 256; off <<= 1) {
        int v = 0;
        if (t < 256 && t >= off) v = bs[t - off];
        __syncthreads();
        if (t < 256) bs[t] += v;
        __syncthreads();
    }
    if (t == 0) { sCnt = gcur[b]; sBase = bs[b] - gcur[b]; }
    hist[t] = 0;
    __syncthreads();
    int cnt = sCnt, gbase = sBase;
    const int2* slab = ebuf + (size_t)b * BCAP;
    for (int e = t; e < cnt; e += 512) {
        int dl = ((unsigned)slab[e].x) >> 23;
        atomicAdd(&hist[dl], 1);
    }
    __syncthreads();
    incl[t] = hist[t];
    __syncthreads();
    for (int off = 1; off < 512; off <<= 1) {
        int v = 0;
        if (t >= off) v = incl[t - off];
        __syncthreads();
        incl[t] += v;
        __syncthreads();
    }
    int ex = incl[t] - hist[t];
    cur[t] = ex;
    if ((t >> 8) == h) {
        int n = (b << 9) + t;
        if (n <= N_NODES) offsets[n] = gbase + ex;
    }
    if (b == NB - 1 && h == 1 && t == 0) offsets[N_NODES] = N_EDGES;
    __syncthreads();
    for (int e = t; e < cnt; e += 512) {
        int2 pk = slab[e];
        int dl = ((unsigned)pk.x) >> 23;
        if ((dl >> 8) == h) {
            int pos = gbase + atomicAdd(&cur[dl], 1);
            int2 rec;
            rec.x = pk.x & 0x7fffff;
            rec.y = pk.y;
            esort[pos] = rec;
        }
    }
}

// ---------------- FUSED agg(layer L) + transform(layer L+1) ----------------
// Block owns 32 nodes: gather-aggregate layer L, tanh, write concat, then
// run the 32->160 transform for the SAME 32 nodes via LDS handoff + MFMA.
// xrel double-buffered across layers (gathers read xrel_in of any node;
// transform writes only own nodes into the OTHER buffer). agg also
// double-buffered (agg_in vs agg_out are distinct allocations).

__global__ __launch_bounds__(256) void k_agg_t(
    const int* __restrict__ offsets, const int2* __restrict__ esort,
    const unsigned int* __restrict__ xrel16, const float* __restrict__ agg,
    float* __restrict__ hout, int hoff,
    const unsigned short* __restrict__ Wbf, const float* __restrict__ bias,
    unsigned short* __restrict__ xs16_out, float* __restrict__ agg_out) {
    __shared__ unsigned int hbf[32][20];   // 32 nodes x 16 bf16-pairs, padded to 20 (80B row, 16B-aligned)
    int t = threadIdx.x;
    int nl = t >> 3;                       // node local 0..31
    int v = blockIdx.x * 32 + nl;          // 3125*32 == N_NODES exactly
    int o = t & 7;
    int s0 = offsets[v], s1 = offsets[v + 1];
    float4 a0 = *(const float4*)(agg + (size_t)v * 32 + o * 4);
    float acc0 = a0.x, acc1 = a0.y, acc2 = a0.z, acc3 = a0.w;
    int last = s1 - 1;
    for (int e = s0; e < s1; e += 16) {
        int addr[16];
        float m[16];
#pragma unroll
        for (int i = 0; i < 16; i++) {
            int ei = e + i;
            int ec = (ei <= last) ? ei : last;
            int2 pk = esort[ec];
            addr[i] = pk.x;
            m[i] = (ei <= last) ? __int_as_float(pk.y) : 0.f;
        }
        uint2 xw[16];
#pragma unroll
        for (int i = 0; i < 16; i++)
            xw[i] = *(const uint2*)(xrel16 + (unsigned)addr[i] + o * 2);
#pragma unroll
        for (int i = 0; i < 16; i++) {
            float f0 = __uint_as_float(xw[i].x << 16);
            float f1 = __uint_as_float(xw[i].x & 0xffff0000u);
            float f2 = __uint_as_float(xw[i].y << 16);
            float f3 = __uint_as_float(xw[i].y & 0xffff0000u);
            acc0 = fmaf(m[i], f0, acc0);
            acc1 = fmaf(m[i], f1, acc1);
            acc2 = fmaf(m[i], f2, acc2);
            acc3 = fmaf(m[i], f3, acc3);
        }
    }
    float4 r;
    r.x = tanhf(acc0); r.y = tanhf(acc1); r.z = tanhf(acc2); r.w = tanhf(acc3);
    *(float4*)(hout + (size_t)v * 96 + hoff + o * 4) = r;
    // LDS handoff: lane holds dims o*4..o*4+3 of node nl (same bf16 rounding
    // point as the old standalone transform which re-read f32 concat).
    hbf[nl][o * 2]     = pack_bf16(r.x, r.y);
    hbf[nl][o * 2 + 1] = pack_bf16(r.z, r.w);
    __syncthreads();
    // ---------- transform for these 32 nodes: 2 groups of 16, 12 tt each ----------
    int wv = t >> 6, lane = t & 63;
    int q = lane >> 4, n16 = lane & 15;
    int gg = wv & 1;                 // group (nodes gg*16..gg*16+15)
    int tbase = (wv >> 1) * 6;       // tts [tbase, tbase+6)
    short8 afr = *(const short8*)&hbf[gg * 16 + n16][q * 4];
    short8 bfr[6];
#pragma unroll
    for (int j = 0; j < 6; j++)
        bfr[j] = *(const short8*)(Wbf + ((tbase + j) * 16 + n16) * 32 + q * 8);
    f32x4 d[6];
    f32x4 z = {0.f, 0.f, 0.f, 0.f};
#pragma unroll
    for (int j = 0; j < 6; j++) d[j] = z;
#pragma unroll
    for (int j = 0; j < 6; j++)
        d[j] = __builtin_amdgcn_mfma_f32_16x16x32_bf16(afr, bfr[j], d[j], 0, 0, 0);
    float bv0 = bias[n16], bv1 = bias[16 + n16];
    int n0 = blockIdx.x * 32 + gg * 16;
#pragma unroll
    for (int j = 0; j < 6; j++) {
        int tt = tbase + j;
        if (tt < 10) {
#pragma unroll
            for (int rr = 0; rr < 4; rr++) {
                int node = n0 + q * 4 + rr;
                xs16_out[(size_t)node * 160 + tt * 16 + n16] = bf16_1(d[j][rr]);
            }
        } else {
            float bv = (tt == 10) ? bv0 : bv1;
            int oo = (tt - 10) * 16 + n16;
#pragma unroll
            for (int rr = 0; rr < 4; rr++) {
                int node = n0 + q * 4 + rr;
                agg_out[(size_t)node * 32 + oo] = d[j][rr] + bv;
            }
        }
    }
}

// ---------------- plain aggregation for the last layer ----------------

__global__ __launch_bounds__(256) void k_agg(
    const int* __restrict__ offsets, const int2* __restrict__ esort,
    const unsigned int* __restrict__ xrel16, const float* __restrict__ agg,
    float* __restrict__ hout, int hoff) {
    int v = blockIdx.x * 32 + (threadIdx.x >> 3);
    int o = threadIdx.x & 7;
    if (v >= N_NODES) return;
    int s0 = offsets[v], s1 = offsets[v + 1];
    float4 a0 = *(const float4*)(agg + (size_t)v * 32 + o * 4);
    float acc0 = a0.x, acc1 = a0.y, acc2 = a0.z, acc3 = a0.w;
    int last = s1 - 1;
    for (int e = s0; e < s1; e += 16) {
        int addr[16];
        float m[16];
#pragma unroll
        for (int i = 0; i < 16; i++) {
            int ei = e + i;
            int ec = (ei <= last) ? ei : last;
            int2 pk = esort[ec];
            addr[i] = pk.x;
            m[i] = (ei <= last) ? __int_as_float(pk.y) : 0.f;
        }
        uint2 xw[16];
#pragma unroll
        for (int i = 0; i < 16; i++)
            xw[i] = *(const uint2*)(xrel16 + (unsigned)addr[i] + o * 2);
#pragma unroll
        for (int i = 0; i < 16; i++) {
            float f0 = __uint_as_float(xw[i].x << 16);
            float f1 = __uint_as_float(xw[i].x & 0xffff0000u);
            float f2 = __uint_as_float(xw[i].y << 16);
            float f3 = __uint_as_float(xw[i].y & 0xffff0000u);
            acc0 = fmaf(m[i], f0, acc0);
            acc1 = fmaf(m[i], f1, acc1);
            acc2 = fmaf(m[i], f2, acc2);
            acc3 = fmaf(m[i], f3, acc3);
        }
    }
    float4 r;
    r.x = tanhf(acc0); r.y = tanhf(acc1); r.z = tanhf(acc2); r.w = tanhf(acc3);
    *(float4*)(hout + (size_t)v * 96 + hoff + o * 4) = r;
}

// ---------------- MLP head ----------------

__global__ void k_mlp(const float* __restrict__ concat, const int* __restrict__ uidx,
                      const int* __restrict__ iidx,
                      const float* __restrict__ w1, const float* __restrict__ bw1,
                      const float* __restrict__ w2, const float* __restrict__ bw2,
                      float* __restrict__ out) {
    __shared__ float feats[192];
    __shared__ float red[2];
    int p = blockIdx.x;
    int t = threadIdx.x;   // 128 threads
    int u = uidx[p], it = iidx[p];
    for (int k = t; k < 192; k += 128)
        feats[k] = (k < 96) ? concat[(size_t)u * 96 + k] : concat[(size_t)it * 96 + (k - 96)];
    __syncthreads();
    float acc = bw1[t];
    for (int k = 0; k < 192; k++) acc += feats[k] * w1[k * 128 + t];
    float h = fmaxf(acc, 0.f);
    float part = h * w2[t];
    for (int off = 32; off > 0; off >>= 1) part += __shfl_down(part, off, 64);
    if ((t & 63) == 0) red[t >> 6] = part;
    __syncthreads();
    if (t == 0) out[p] = red[0] + red[1] + bw2[0];
}

// ---------------- launch ----------------

extern "C" void kernel_launch(void* const* d_in, const int* in_sizes, int n_in,
                              void* d_out, int out_size, void* d_ws, size_t ws_size,
                              hipStream_t stream) {
    const float* x         = (const float*)d_in[0];
    const float* edge_mask = (const float*)d_in[1];
    const int*   etype     = (const int*)d_in[2];
    const int*   src       = (const int*)d_in[3];
    const int*   dst       = (const int*)d_in[4];
    const int*   users_idx = (const int*)d_in[5];
    const int*   items_idx = (const int*)d_in[6];
    const float* V1        = (const float*)d_in[7];
    const float* comp1     = (const float*)d_in[8];
    const float* loop1     = (const float*)d_in[9];
    const float* b1        = (const float*)d_in[10];
    const float* V2        = (const float*)d_in[11];
    const float* comp2     = (const float*)d_in[12];
    const float* loop2     = (const float*)d_in[13];
    const float* b2        = (const float*)d_in[14];
    const float* V3        = (const float*)d_in[15];
    const float* comp3     = (const float*)d_in[16];
    const float* loop3     = (const float*)d_in[17];
    const float* b3        = (const float*)d_in[18];
    const float* w1        = (const float*)d_in[19];
    const float* bw1       = (const float*)d_in[20];
    const float* w2        = (const float*)d_in[21];
    const float* bw2       = (const float*)d_in[22];
    float* out = (float*)d_out;

    uintptr_t w = (uintptr_t)d_ws;
    auto al = [&](size_t bytes) { uintptr_t p = (w + 255) & ~(uintptr_t)255; w = p + bytes; return p; };
    int*   gcur    = (int*)al(sizeof(int) * NB);
    int*   offsets = (int*)al(sizeof(int) * (N_NODES + 1));
    int2*  ebuf    = (int2*)al(sizeof(int2) * (size_t)NB * BCAP);   // fixed slabs
    unsigned int* xrelA = (unsigned int*)al(sizeof(unsigned int) * (size_t)N_NODES * 80);
    unsigned int* xrelB = (unsigned int*)al(sizeof(unsigned int) * (size_t)N_NODES * 80);
    int2*  esort   = (int2*)al(sizeof(int2) * N_EDGES);
    unsigned short* Wbf1 = (unsigned short*)al(sizeof(unsigned short) * 192 * IN_FEATS);
    unsigned short* Wbf2 = (unsigned short*)al(sizeof(unsigned short) * 192 * HID);
    unsigned short* Wbf3 = (unsigned short*)al(sizeof(unsigned short) * 192 * HID);
    float* aggA    = (float*)al(sizeof(float) * (size_t)N_NODES * 32);
    float* aggB    = (float*)al(sizeof(float) * (size_t)N_NODES * 32);
    float* concat  = (float*)al(sizeof(float) * (size_t)N_NODES * 96);

    // weight prep + gcur zeroing (replaces memset dispatch)
    k_wprep<<<144, 256, 0, stream>>>(V1, comp1, loop1, V2, comp2, loop2,
                                     V3, comp3, loop3, Wbf1, Wbf2, Wbf3, gcur);
    // scatter (independent of weights) overlapped with transform L1
    k_fused1<<<SC_BLOCKS + TL1_BLOCKS, 256, 0, stream>>>(
        src, dst, etype, edge_mask, gcur, ebuf,
        x, Wbf1, b1, (unsigned short*)xrelA, aggA);
    k_bsort2<<<2 * NB, 512, 0, stream>>>(gcur, ebuf, esort, offsets);

    const int agrid = N_NODES / 32;   // 3125, exact

    // layer 1 agg + layer 2 transform (gather A, write B)
    k_agg_t<<<agrid, 256, 0, stream>>>(offsets, esort, xrelA, aggA, concat, 0,
                                       Wbf2, b2, (unsigned short*)xrelB, aggB);
    // layer 2 agg + layer 3 transform (gather B, write A)
    k_agg_t<<<agrid, 256, 0, stream>>>(offsets, esort, xrelB, aggB, concat, 32,
                                       Wbf3, b3, (unsigned short*)xrelA, aggA);
    // layer 3 agg
    k_agg<<<agrid, 256, 0, stream>>>(offsets, esort, xrelA, aggA, concat, 64);

    k_mlp<<<N_PAIRS, 128, 0, stream>>>(concat, users_idx, items_idx, w1, bw1, w2, bw2, out);
}

// Round 4
// 318.468 us; speedup vs baseline: 1.1203x; 1.0850x over previous
//
#include <hip/hip_runtime.h>
#include <stdint.h>

#define N_NODES  100000
#define N_EDGES  1600000
#define IN_FEATS 128
#define HID      32
#define N_REL    5
#define N_BASES  2
#define N_PAIRS  4096

#define NB        196        // buckets of 512 dst nodes
#define BCAP      16384      // fixed slab per bucket (mean 8192, sigma ~90)
#define EPB       2048       // edges per scatter block
#define SC_BLOCKS 782        // ceil(1600000/2048)
#define TL1_BLOCKS 1250      // 6250 groups / 5
#define NGROUPS   6250       // N_NODES/16

typedef __attribute__((ext_vector_type(8))) short short8;
typedef __attribute__((ext_vector_type(4))) float f32x4;

__device__ inline unsigned int pack_bf16(float a, float b) {
    unsigned int ua = __float_as_uint(a), ub = __float_as_uint(b);
    ua = (ua + 0x7fffu + ((ua >> 16) & 1u)) >> 16;
    ub = (ub + 0x7fffu + ((ub >> 16) & 1u)) >> 16;
    return ua | (ub << 16);
}

__device__ inline unsigned short bf16_1(float a) {
    unsigned int u = __float_as_uint(a);
    u = (u + 0x7fffu + ((u >> 16) & 1u)) >> 16;
    return (unsigned short)u;
}

// split pair (a,b) into bf16 hi word + bf16 lo (residual) word
__device__ inline void split_bf16_2(float a, float b, unsigned int& hi, unsigned int& lo) {
    unsigned int ha = bf16_1(a), hb = bf16_1(b);
    hi = ha | (hb << 16);
    float fa = __uint_as_float(ha << 16), fb = __uint_as_float(hb << 16);
    lo = pack_bf16(a - fa, b - fb);
}

// ---------------- weight prep + gcur zeroing ----------------
// Wbf1: layer-1 comp-combined W_r (12 tts x 16 cols x 128 k)
// Wcat2/3: layers 2/3 raw-basis split weights [32 outcols][160 k]:
//   seg = k/32, inner = k%32
//   seg 0,1 -> V[b=0][inner][col]   (y0 hi, y0 lo)
//   seg 2,3 -> V[b=1][inner][col]   (y1 hi, y1 lo)
//   seg 4   -> loopw[inner][col]    (h_own)

__global__ __launch_bounds__(256) void k_wprep(
    const float* __restrict__ V1, const float* __restrict__ comp1, const float* __restrict__ loop1,
    const float* __restrict__ V2, const float* __restrict__ loop2,
    const float* __restrict__ V3, const float* __restrict__ loop3,
    unsigned short* __restrict__ Wbf1, unsigned short* __restrict__ Wcat2,
    unsigned short* __restrict__ Wcat3, int* __restrict__ gcur) {
    int b = blockIdx.x;
    int t = threadIdx.x;
    if (b == 0 && t < NB) gcur[t] = 0;
    if (b < 96) {
        int idx = b * 256 + t;
        if (idx >= 192 * IN_FEATS) return;
        int j = idx / IN_FEATS, k = idx % IN_FEATS;
        float v;
        if (j < 160) {
            int r = j >> 5, o = j & 31;
            v = comp1[r * 2 + 0] * V1[(size_t)(0 * IN_FEATS + k) * 32 + o]
              + comp1[r * 2 + 1] * V1[(size_t)(1 * IN_FEATS + k) * 32 + o];
        } else {
            v = loop1[k * 32 + (j - 160)];
        }
        Wbf1[idx] = bf16_1(v);
        return;
    }
    // Wcat2 / Wcat3: 32*160 = 5120 entries each (20 blocks per layer)
    const float *V, *loopw;
    unsigned short* Wc;
    int idx;
    if (b < 116) { V = V2; loopw = loop2; Wc = Wcat2; idx = (b - 96) * 256 + t; }
    else         { V = V3; loopw = loop3; Wc = Wcat3; idx = (b - 116) * 256 + t; }
    if (idx >= 32 * 160) return;
    int col = idx / 160, k = idx % 160;
    int seg = k >> 5, inner = k & 31;
    float v;
    if (seg < 2)      v = V[inner * 32 + col];           // basis 0 (hi, lo)
    else if (seg < 4) v = V[(32 + inner) * 32 + col];    // basis 1 (hi, lo)
    else              v = loopw[inner * 32 + col];       // self-loop
    Wc[idx] = bf16_1(v);
}

// ---------------- FUSED: edge scatter (blocks 0..781) + transform L1 ----------
// scatter record: x = (dst&511)<<23 | (src<<4) | etype, y = mask fp32

__global__ __launch_bounds__(256) void k_fused1(
    const int* __restrict__ src, const int* __restrict__ dst,
    const int* __restrict__ etype, const float* __restrict__ mask,
    int* __restrict__ gcur, int2* __restrict__ ebuf,
    const float* __restrict__ xin,
    const unsigned short* __restrict__ Wbf, const float* __restrict__ bias,
    unsigned short* __restrict__ xs16, float* __restrict__ aggout) {
    int b = blockIdx.x;
    int t = threadIdx.x;
    if (b < SC_BLOCKS) {
        __shared__ int lh[NB];
        __shared__ int lex[NB];
        __shared__ int gbase[NB];
        __shared__ int scanbuf[256];
        __shared__ int2  srec[EPB];
        __shared__ short sb[EPB];
        int e0 = b * EPB;
        if (t < NB) lh[t] = 0;
        __syncthreads();
        int2 rec[8];
        int  bk[8];
#pragma unroll
        for (int i = 0; i < 8; i++) {
            int e = e0 + t + i * 256;
            if (e < N_EDGES) {
                int d = dst[e];
                bk[i] = d >> 9;
                rec[i].x = ((d & 511) << 23) | (src[e] << 4) | etype[e];
                rec[i].y = __float_as_int(mask[e]);
                atomicAdd(&lh[bk[i]], 1);
            } else bk[i] = -1;
        }
        __syncthreads();
        int cnt = (t < NB) ? lh[t] : 0;
        scanbuf[t] = cnt;
        __syncthreads();
        for (int off = 1; off < 256; off <<= 1) {
            int v = (t >= off) ? scanbuf[t - off] : 0;
            __syncthreads();
            scanbuf[t] += v;
            __syncthreads();
        }
        if (t < NB) {
            lex[t] = scanbuf[t] - cnt;
            gbase[t] = t * BCAP + (cnt ? atomicAdd(&gcur[t], cnt) : 0);
            lh[t] = 0;
        }
        __syncthreads();
#pragma unroll
        for (int i = 0; i < 8; i++) {
            if (bk[i] >= 0) {
                int p = lex[bk[i]] + atomicAdd(&lh[bk[i]], 1);
                srec[p] = rec[i];
                sb[p] = (short)bk[i];
            }
        }
        __syncthreads();
        int total = scanbuf[NB - 1];
        for (int idx = t; idx < total; idx += 256) {
            int bb = sb[idx];
            ebuf[gbase[bb] + (idx - lex[bb])] = srec[idx];
        }
        return;
    }
    // ---------- transform L1 (D=128): wave-specialized MFMA ----------
    __shared__ unsigned short As[16 * 136];
    int bb = b - SC_BLOCKS;
    int wv = t >> 6, lane = t & 63;
    int q = lane >> 4, n16 = lane & 15;
    short8 bfr[3][4];
#pragma unroll
    for (int i = 0; i < 3; i++) {
        int tt = wv * 3 + i;
#pragma unroll
        for (int ks = 0; ks < 4; ks++)
            bfr[i][ks] = *(const short8*)(Wbf + (tt * 16 + n16) * 128 + ks * 32 + q * 8);
    }
    float bv0 = bias[n16], bv1 = bias[16 + n16];
    int node_l = t >> 4;
    int seg    = t & 15;
    int g0 = bb * 5;
    float4 p0, p1;
    {
        const float* xr = xin + ((size_t)(g0 * 16 + node_l)) * 128 + seg * 8;
        p0 = *(const float4*)xr;
        p1 = *(const float4*)(xr + 4);
    }
    for (int gi = 0; gi < 5; gi++) {
        int g = g0 + gi;
        int n0 = g * 16;
        __syncthreads();
        {
            unsigned int u0 = pack_bf16(p0.x, p0.y);
            unsigned int u1 = pack_bf16(p0.z, p0.w);
            unsigned int u2 = pack_bf16(p1.x, p1.y);
            unsigned int u3 = pack_bf16(p1.z, p1.w);
            uint4 v; v.x = u0; v.y = u1; v.z = u2; v.w = u3;
            *(uint4*)(As + node_l * 136 + seg * 8) = v;
        }
        __syncthreads();
        if (gi + 1 < 5) {
            const float* xr = xin + ((size_t)((g + 1) * 16 + node_l)) * 128 + seg * 8;
            p0 = *(const float4*)xr;
            p1 = *(const float4*)(xr + 4);
        }
        short8 afr[4];
#pragma unroll
        for (int ks = 0; ks < 4; ks++)
            afr[ks] = *(const short8*)(As + n16 * 136 + ks * 32 + q * 8);
        f32x4 d[3];
        f32x4 z = {0.f, 0.f, 0.f, 0.f};
#pragma unroll
        for (int i = 0; i < 3; i++) d[i] = z;
#pragma unroll
        for (int i = 0; i < 3; i++)
#pragma unroll
            for (int ks = 0; ks < 4; ks++)
                d[i] = __builtin_amdgcn_mfma_f32_16x16x32_bf16(afr[ks], bfr[i][ks], d[i], 0, 0, 0);
#pragma unroll
        for (int i = 0; i < 3; i++) {
            int tt = wv * 3 + i;
            if (tt < 10) {
#pragma unroll
                for (int r = 0; r < 4; r++) {
                    int node = n0 + q * 4 + r;
                    xs16[(size_t)node * 160 + tt * 16 + n16] = bf16_1(d[i][r]);
                }
            } else {
                float bv = (tt == 10) ? bv0 : bv1;
                int o = (tt - 10) * 16 + n16;
#pragma unroll
                for (int r = 0; r < 4; r++) {
                    int node = n0 + q * 4 + r;
                    aggout[(size_t)node * 32 + o] = d[i][r] + bv;
                }
            }
        }
    }
}

// ---------------- per-half-bucket counting sort -> contiguous CSR ----------------

__global__ __launch_bounds__(512) void k_bsort2(
    const int* __restrict__ gcur, const int2* __restrict__ ebuf,
    int2* __restrict__ esort, int* __restrict__ offsets) {
    __shared__ int hist[512];
    __shared__ int incl[512];
    __shared__ int cur[512];
    __shared__ int bs[256];
    __shared__ int sBase, sCnt;
    int blk = blockIdx.x, b = blk >> 1, h = blk & 1, t = threadIdx.x;
    if (t < 256) bs[t] = (t < NB) ? gcur[t] : 0;
    __syncthreads();
    for (int off = 1; off < 256; off <<= 1) {
        int v = 0;
        if (t < 256 && t >= off) v = bs[t - off];
        __syncthreads();
        if (t < 256) bs[t] += v;
        __syncthreads();
    }
    if (t == 0) { sCnt = gcur[b]; sBase = bs[b] - gcur[b]; }
    hist[t] = 0;
    __syncthreads();
    int cnt = sCnt, gbase = sBase;
    const int2* slab = ebuf + (size_t)b * BCAP;
    for (int e = t; e < cnt; e += 512) {
        int dl = ((unsigned)slab[e].x) >> 23;
        atomicAdd(&hist[dl], 1);
    }
    __syncthreads();
    incl[t] = hist[t];
    __syncthreads();
    for (int off = 1; off < 512; off <<= 1) {
        int v = 0;
        if (t >= off) v = incl[t - off];
        __syncthreads();
        incl[t] += v;
        __syncthreads();
    }
    int ex = incl[t] - hist[t];
    cur[t] = ex;
    if ((t >> 8) == h) {
        int n = (b << 9) + t;
        if (n <= N_NODES) offsets[n] = gbase + ex;
    }
    if (b == NB - 1 && h == 1 && t == 0) offsets[N_NODES] = N_EDGES;
    __syncthreads();
    for (int e = t; e < cnt; e += 512) {
        int2 pk = slab[e];
        int dl = ((unsigned)pk.x) >> 23;
        if ((dl >> 8) == h) {
            int pos = gbase + atomicAdd(&cur[dl], 1);
            int2 rec;
            rec.x = pk.x & 0x7fffff;
            rec.y = pk.y;
            esort[pos] = rec;
        }
    }
}

// ---------------- layer-1 aggregation (gathers per-etype xs16) ----------------

__global__ __launch_bounds__(256) void k_agg1(
    const int* __restrict__ offsets, const int2* __restrict__ esort,
    const unsigned int* __restrict__ xrel16, const float* __restrict__ agg,
    float* __restrict__ concat, unsigned int* __restrict__ hrel_out) {
    int v = blockIdx.x * 32 + (threadIdx.x >> 3);
    int o = threadIdx.x & 7;
    int s0 = offsets[v], s1 = offsets[v + 1];
    float4 a0 = *(const float4*)(agg + (size_t)v * 32 + o * 4);
    float acc0 = a0.x, acc1 = a0.y, acc2 = a0.z, acc3 = a0.w;
    int last = s1 - 1;
    for (int e = s0; e < s1; e += 16) {
        int addr[16];
        float m[16];
#pragma unroll
        for (int i = 0; i < 16; i++) {
            int ei = e + i;
            int ec = (ei <= last) ? ei : last;
            int2 pk = esort[ec];
            int low = pk.x;
            addr[i] = (low >> 4) * 80 + (low & 15) * 16;
            m[i] = (ei <= last) ? __int_as_float(pk.y) : 0.f;
        }
        uint2 xw[16];
#pragma unroll
        for (int i = 0; i < 16; i++)
            xw[i] = *(const uint2*)(xrel16 + (unsigned)addr[i] + o * 2);
#pragma unroll
        for (int i = 0; i < 16; i++) {
            float f0 = __uint_as_float(xw[i].x << 16);
            float f1 = __uint_as_float(xw[i].x & 0xffff0000u);
            float f2 = __uint_as_float(xw[i].y << 16);
            float f3 = __uint_as_float(xw[i].y & 0xffff0000u);
            acc0 = fmaf(m[i], f0, acc0);
            acc1 = fmaf(m[i], f1, acc1);
            acc2 = fmaf(m[i], f2, acc2);
            acc3 = fmaf(m[i], f3, acc3);
        }
    }
    float4 r;
    r.x = tanhf(acc0); r.y = tanhf(acc1); r.z = tanhf(acc2); r.w = tanhf(acc3);
    *(float4*)(concat + (size_t)v * 96 + o * 4) = r;
    hrel_out[v * 16 + o * 2]     = pack_bf16(r.x, r.y);
    hrel_out[v * 16 + o * 2 + 1] = pack_bf16(r.z, r.w);
}

// ---------------- layers 2/3: basis-space aggregation + split-bf16 MFMA epilogue ----------
// y_b[v] = sum_e m*comp[r,b]*h_src  (h gathered raw: 64B/node, 6.4MB L2-resident)
// h_out = tanh( [y0hi|y0lo|y1hi|y1lo|h_own](160) @ [V0;V0;V1;V1;loop](160x32) + bias )
// The hi/lo split keeps y at ~2^-17 relative precision through the bf16 MFMA.

__global__ __launch_bounds__(256) void k_agg23(
    const int* __restrict__ offsets, const int2* __restrict__ esort,
    const unsigned int* __restrict__ hrel_in, const float* __restrict__ comp,
    const unsigned short* __restrict__ Wcat, const float* __restrict__ bias,
    float* __restrict__ concat, int hoff, unsigned int* __restrict__ hrel_out) {
    __shared__ unsigned int hbf[32][84];   // 80 uints used (160 bf16), 336B row (16B-aligned)
    __shared__ float2 cLds[5];
    int t = threadIdx.x;
    if (t < 5) cLds[t] = ((const float2*)comp)[t];
    int nl = t >> 3;
    int v = blockIdx.x * 32 + nl;
    int o = t & 7;
    int s0 = offsets[v], s1 = offsets[v + 1];
    __syncthreads();
    float y00 = 0.f, y01 = 0.f, y02 = 0.f, y03 = 0.f;
    float y10 = 0.f, y11 = 0.f, y12 = 0.f, y13 = 0.f;
    int last = s1 - 1;
    for (int e = s0; e < s1; e += 16) {
        int addr[16];
        float c0[16], c1[16];
#pragma unroll
        for (int i = 0; i < 16; i++) {
            int ei = e + i;
            int ec = (ei <= last) ? ei : last;
            int2 pk = esort[ec];
            int low = pk.x;
            addr[i] = low & 0x7ffff0;            // src*16 (uint units)
            float2 cc = cLds[low & 15];
            float m = (ei <= last) ? __int_as_float(pk.y) : 0.f;
            c0[i] = m * cc.x;
            c1[i] = m * cc.y;
        }
        uint2 xw[16];
#pragma unroll
        for (int i = 0; i < 16; i++)
            xw[i] = *(const uint2*)(hrel_in + (unsigned)addr[i] + o * 2);
#pragma unroll
        for (int i = 0; i < 16; i++) {
            float f0 = __uint_as_float(xw[i].x << 16);
            float f1 = __uint_as_float(xw[i].x & 0xffff0000u);
            float f2 = __uint_as_float(xw[i].y << 16);
            float f3 = __uint_as_float(xw[i].y & 0xffff0000u);
            y00 = fmaf(c0[i], f0, y00); y10 = fmaf(c1[i], f0, y10);
            y01 = fmaf(c0[i], f1, y01); y11 = fmaf(c1[i], f1, y11);
            y02 = fmaf(c0[i], f2, y02); y12 = fmaf(c1[i], f2, y12);
            y03 = fmaf(c0[i], f3, y03); y13 = fmaf(c1[i], f3, y13);
        }
    }
    // stage [y0hi | y0lo | y1hi | y1lo | h_own] as bf16 rows of the MFMA A-tile
    unsigned int hi, lo;
    split_bf16_2(y00, y01, hi, lo);
    hbf[nl][o * 2]          = hi;  hbf[nl][16 + o * 2]     = lo;
    split_bf16_2(y02, y03, hi, lo);
    hbf[nl][o * 2 + 1]      = hi;  hbf[nl][16 + o * 2 + 1] = lo;
    split_bf16_2(y10, y11, hi, lo);
    hbf[nl][32 + o * 2]     = hi;  hbf[nl][48 + o * 2]     = lo;
    split_bf16_2(y12, y13, hi, lo);
    hbf[nl][32 + o * 2 + 1] = hi;  hbf[nl][48 + o * 2 + 1] = lo;
    *(uint2*)&hbf[nl][64 + o * 2] = *(const uint2*)(hrel_in + v * 16 + o * 2);
    __syncthreads();
    // ---------- MFMA: 2 node-groups x 2 out-tiles x 5 ksteps ----------
    int wv = t >> 6, lane = t & 63;
    int q = lane >> 4, n16 = lane & 15;
    int gg = wv & 1;
    int tt = wv >> 1;
    f32x4 d = {0.f, 0.f, 0.f, 0.f};
#pragma unroll
    for (int ks = 0; ks < 5; ks++) {
        short8 afr = *(const short8*)&hbf[gg * 16 + n16][ks * 16 + q * 4];
        short8 bfr = *(const short8*)(Wcat + (tt * 16 + n16) * 160 + ks * 32 + q * 8);
        d = __builtin_amdgcn_mfma_f32_16x16x32_bf16(afr, bfr, d, 0, 0, 0);
    }
    float bv = bias[tt * 16 + n16];
    int n0 = blockIdx.x * 32 + gg * 16;
#pragma unroll
    for (int r = 0; r < 4; r++) {
        int node = n0 + q * 4 + r;
        float h = tanhf(d[r] + bv);
        concat[(size_t)node * 96 + hoff + tt * 16 + n16] = h;
        if (hrel_out)
            ((unsigned short*)hrel_out)[node * 32 + tt * 16 + n16] = bf16_1(h);
    }
}

// ---------------- MLP head ----------------

__global__ void k_mlp(const float* __restrict__ concat, const int* __restrict__ uidx,
                      const int* __restrict__ iidx,
                      const float* __restrict__ w1, const float* __restrict__ bw1,
                      const float* __restrict__ w2, const float* __restrict__ bw2,
                      float* __restrict__ out) {
    __shared__ float feats[192];
    __shared__ float red[2];
    int p = blockIdx.x;
    int t = threadIdx.x;   // 128 threads
    int u = uidx[p], it = iidx[p];
    for (int k = t; k < 192; k += 128)
        feats[k] = (k < 96) ? concat[(size_t)u * 96 + k] : concat[(size_t)it * 96 + (k - 96)];
    __syncthreads();
    float acc = bw1[t];
    for (int k = 0; k < 192; k++) acc += feats[k] * w1[k * 128 + t];
    float h = fmaxf(acc, 0.f);
    float part = h * w2[t];
    for (int off = 32; off > 0; off >>= 1) part += __shfl_down(part, off, 64);
    if ((t & 63) == 0) red[t >> 6] = part;
    __syncthreads();
    if (t == 0) out[p] = red[0] + red[1] + bw2[0];
}

// ---------------- launch ----------------

extern "C" void kernel_launch(void* const* d_in, const int* in_sizes, int n_in,
                              void* d_out, int out_size, void* d_ws, size_t ws_size,
                              hipStream_t stream) {
    const float* x         = (const float*)d_in[0];
    const float* edge_mask = (const float*)d_in[1];
    const int*   etype     = (const int*)d_in[2];
    const int*   src       = (const int*)d_in[3];
    const int*   dst       = (const int*)d_in[4];
    const int*   users_idx = (const int*)d_in[5];
    const int*   items_idx = (const int*)d_in[6];
    const float* V1        = (const float*)d_in[7];
    const float* comp1     = (const float*)d_in[8];
    const float* loop1     = (const float*)d_in[9];
    const float* b1        = (const float*)d_in[10];
    const float* V2        = (const float*)d_in[11];
    const float* comp2     = (const float*)d_in[12];
    const float* loop2     = (const float*)d_in[13];
    const float* b2        = (const float*)d_in[14];
    const float* V3        = (const float*)d_in[15];
    const float* comp3     = (const float*)d_in[16];
    const float* loop3     = (const float*)d_in[17];
    const float* b3        = (const float*)d_in[18];
    const float* w1        = (const float*)d_in[19];
    const float* bw1       = (const float*)d_in[20];
    const float* w2        = (const float*)d_in[21];
    const float* bw2       = (const float*)d_in[22];
    float* out = (float*)d_out;

    uintptr_t w = (uintptr_t)d_ws;
    auto al = [&](size_t bytes) { uintptr_t p = (w + 255) & ~(uintptr_t)255; w = p + bytes; return p; };
    int*   gcur    = (int*)al(sizeof(int) * NB);
    int*   offsets = (int*)al(sizeof(int) * (N_NODES + 1));
    int2*  ebuf    = (int2*)al(sizeof(int2) * (size_t)NB * BCAP);
    unsigned int* xs16  = (unsigned int*)al(sizeof(unsigned int) * (size_t)N_NODES * 80);
    unsigned int* hrel1 = (unsigned int*)al(sizeof(unsigned int) * (size_t)N_NODES * 16);
    unsigned int* hrel2 = (unsigned int*)al(sizeof(unsigned int) * (size_t)N_NODES * 16);
    int2*  esort   = (int2*)al(sizeof(int2) * N_EDGES);
    unsigned short* Wbf1  = (unsigned short*)al(sizeof(unsigned short) * 192 * IN_FEATS);
    unsigned short* Wcat2 = (unsigned short*)al(sizeof(unsigned short) * 32 * 160);
    unsigned short* Wcat3 = (unsigned short*)al(sizeof(unsigned short) * 32 * 160);
    float* aggA    = (float*)al(sizeof(float) * (size_t)N_NODES * 32);
    float* concat  = (float*)al(sizeof(float) * (size_t)N_NODES * 96);

    k_wprep<<<136, 256, 0, stream>>>(V1, comp1, loop1, V2, loop2, V3, loop3,
                                     Wbf1, Wcat2, Wcat3, gcur);
    k_fused1<<<SC_BLOCKS + TL1_BLOCKS, 256, 0, stream>>>(
        src, dst, etype, edge_mask, gcur, ebuf,
        x, Wbf1, b1, (unsigned short*)xs16, aggA);
    k_bsort2<<<2 * NB, 512, 0, stream>>>(gcur, ebuf, esort, offsets);

    const int agrid = N_NODES / 32;   // 3125, exact

    // layer 1 aggregation -> h1 (concat[:,0:32] f32 + hrel1 bf16)
    k_agg1<<<agrid, 256, 0, stream>>>(offsets, esort, xs16, aggA, concat, hrel1);
    // layer 2: gather h1, basis-accumulate, split-bf16 MFMA epilogue -> h2
    k_agg23<<<agrid, 256, 0, stream>>>(offsets, esort, hrel1, comp2, Wcat2, b2,
                                       concat, 32, hrel2);
    // layer 3 -> h3 (no hrel_out needed)
    k_agg23<<<agrid, 256, 0, stream>>>(offsets, esort, hrel2, comp3, Wcat3, b3,
                                       concat, 64, (unsigned int*)nullptr);

    k_mlp<<<N_PAIRS, 128, 0, stream>>>(concat, users_idx, items_idx, w1, bw1, w2, bw2, out);
}